// Round 7
// baseline (234.736 us; speedup 1.0000x reference)
//
#include <hip/hip_runtime.h>
#include <math.h>

// SimpleGCN: h1 = relu(GCN(x,W1,b1)); h2 = relu(GCN(h1,W2,b2));
// g = mean(h2, axis=0); out = (g@Wr + br) -> 128 fp32.
// GCN(x,W,b)[d] = dinv[d]*( sum_{s in N(d)} y[s] + y[d] ) + b,
//   y = dinv * (x@W), dinv[i] = (1+indeg[i])^-0.5.
//
// R6 post-mortem: no dominant dispatch left (top-5 = harness ws-poison).
// R7: (a) aggregate index-prefetch — one coalesced csr_src load of <=64
// indices per node, then __shfl-sourced indices (30cyc) replace the L2
// index load (200cyc) in the gather chain; (b) GEMM2 fused into aggregate-1:
// after the butterfly every lane holds the full h1 row, so y2=dinv*(h1@W2)
// is 16x(4 shfl + 4 LDS + 4 FMA) in-kernel — deletes a kernel + 25.6MB of
// h round-trip traffic.

#define CH 4096    // edges per chunk-block in hist/scatter
#define MAXNB 1024 // NB = ceil(n/64) <= 1024 (n <= 65536)

__global__ __launch_bounds__(256) void k_bucket_hist(const int* __restrict__ dst,
                                                     int* __restrict__ histmat,
                                                     int E, int NB) {
    __shared__ int ih[MAXNB];
    int t = threadIdx.x;
    for (int k = t; k < NB; k += 256) ih[k] = 0;
    __syncthreads();
    int base = blockIdx.x * CH;
    for (int i = 0; i < CH; i += 256) {
        int e = base + i + t;
        if (e < E) atomicAdd(&ih[dst[e] >> 6], 1);
    }
    __syncthreads();
    for (int k = t; k < NB; k += 256) histmat[(size_t)blockIdx.x * NB + k] = ih[k];
}

// thread per bucket: exclusive prefix over chunks (column of chunk-major
// histmat) in place + per-bucket total. Coalesced; unroll-8 load batches.
__global__ __launch_bounds__(256) void k_colscan(int* __restrict__ histmat,
                                                 int* __restrict__ tot,
                                                 int NB, int nch) {
    int k = blockIdx.x * 256 + threadIdx.x;
    if (k >= NB) return;
    int run = 0;
    int b = 0;
    for (; b + 8 <= nch; b += 8) {
        int v[8];
#pragma unroll
        for (int u = 0; u < 8; u++) v[u] = histmat[(size_t)(b + u) * NB + k];
#pragma unroll
        for (int u = 0; u < 8; u++) {
            int x = v[u];
            histmat[(size_t)(b + u) * NB + k] = run;
            run += x;
        }
    }
    for (; b < nch; b++) {
        int x = histmat[(size_t)b * NB + k];
        histmat[(size_t)b * NB + k] = run;
        run += x;
    }
    tot[k] = run;
}

// single block: exclusive scan of NB (<=1024) totals -> bstart; tails.
__global__ __launch_bounds__(256) void k_scanb(const int* __restrict__ tot,
                                               int* __restrict__ bstart,
                                               int* __restrict__ offsets,
                                               int NB, int E, int n) {
    __shared__ int sc[256];
    __shared__ int carry;
    int t = threadIdx.x;
    if (t == 0) carry = 0;
    __syncthreads();
    int nchunk = (NB + 255) / 256;
    for (int c = 0; c < nchunk; c++) {
        int idx = c * 256 + t;
        int v = (idx < NB) ? tot[idx] : 0;
        sc[t] = v;
        __syncthreads();
        for (int off = 1; off < 256; off <<= 1) {
            int x = (t >= off) ? sc[t - off] : 0;
            __syncthreads();
            sc[t] += x;
            __syncthreads();
        }
        if (idx < NB) bstart[idx] = sc[t] - v + carry;
        __syncthreads();
        if (t == 0) carry += sc[255];
        __syncthreads();
    }
    if (t == 0) { bstart[NB] = E; offsets[n] = E; }
}

__global__ __launch_bounds__(256) void k_bucket_scatter(const int* __restrict__ src,
                                                        const int* __restrict__ dst,
                                                        const int* __restrict__ histmat,
                                                        const int* __restrict__ bstart,
                                                        int* __restrict__ staged,
                                                        int E, int NB) {
    __shared__ int cur[MAXNB];
    int t = threadIdx.x;
    for (int k = t; k < NB; k += 256)
        cur[k] = bstart[k] + histmat[(size_t)blockIdx.x * NB + k];
    __syncthreads();
    int base = blockIdx.x * CH;
    for (int i = 0; i < CH; i += 256) {
        int e = base + i + t;
        if (e < E) {
            int d = dst[e];
            int pos = atomicAdd(&cur[d >> 6], 1);
            staged[pos] = (src[e] << 6) | (d & 63);  // n<=65536 -> fits
        }
    }
}

// one block per bucket: counting-sort the bucket's staged run into node-
// granular CSR; emit per-node offsets + dinv from the counts.
__global__ __launch_bounds__(256) void k_local_sort(const int* __restrict__ staged,
                                                    const int* __restrict__ bstart,
                                                    int* __restrict__ csr_src,
                                                    int* __restrict__ offsets,
                                                    float* __restrict__ dinv, int n) {
    __shared__ int cnt[64];
    __shared__ int pos[64];
    __shared__ int cur[64];
    int t = threadIdx.x;
    if (t < 64) cnt[t] = 0;
    __syncthreads();
    int k = blockIdx.x;
    int beg = bstart[k], end = bstart[k + 1];
    for (int e = beg + t; e < end; e += 256) atomicAdd(&cnt[staged[e] & 63], 1);
    __syncthreads();
    if (t == 0) {
        int run = 0;
        for (int i = 0; i < 64; i++) { pos[i] = run; run += cnt[i]; }
    }
    __syncthreads();
    if (t < 64) {
        cur[t] = pos[t];
        int node = k * 64 + t;
        if (node < n) {
            offsets[node] = beg + pos[t];
            dinv[node] = 1.0f / sqrtf((float)(cnt[t] + 1));  // + self-loop
        }
    }
    __syncthreads();
    for (int e = beg + t; e < end; e += 256) {
        int pk = staged[e];
        int p = atomicAdd(&cur[pk & 63], 1);
        csr_src[beg + p] = pk >> 6;
    }
}

// Y[i,:] = dinv[i] * (X[i,:] @ W). 16 rows/block, 4 rows/wave.
__global__ __launch_bounds__(256) void k_gemm_scale(const float* __restrict__ X,
                                                    const float* __restrict__ W,
                                                    const float* __restrict__ dinv,
                                                    float* __restrict__ Y, int n) {
    __shared__ float Ws[64 * 64];
    __shared__ float xs[16][64];
    int t = threadIdx.x, w = t >> 6, f = t & 63;
    const float4* W4 = (const float4*)W;
    float4* Ws4 = (float4*)Ws;
#pragma unroll
    for (int j = 0; j < 4; j++) Ws4[t + 256 * j] = W4[t + 256 * j];
    int r0 = blockIdx.x * 16;
#pragma unroll
    for (int i = 0; i < 4; i++) {
        int r = r0 + w * 4 + i;
        xs[w * 4 + i][f] = (r < n) ? X[(size_t)r * 64 + f] : 0.f;
    }
    __syncthreads();
    float acc[4] = {0.f, 0.f, 0.f, 0.f};
#pragma unroll 8
    for (int k = 0; k < 64; k++) {
        float wv = Ws[k * 64 + f];
#pragma unroll
        for (int i = 0; i < 4; i++) acc[i] += xs[w * 4 + i][k] * wv;
    }
#pragma unroll
    for (int i = 0; i < 4; i++) {
        int r = r0 + w * 4 + i;
        if (r < n) Y[(size_t)r * 64 + f] = dinv[r] * acc[i];
    }
}

// One wave per node. lane = (q,c): q=lane>>4 edge slot, c=lane&15 float4 col.
// Up to 64 neighbor indices preloaded with ONE coalesced load, then sourced
// via __shfl (30cyc) instead of an L2 load (200cyc). Cross-slot reduce:
// shfl_xor(16,32) -> ALL lanes hold the full h row.
// FUSE: epilogue computes Yout = dinv*(h@Wf) via shfl-broadcast + LDS Wf.
// POOL: per-block partial mean rows into pbuf.
template <bool FUSE, bool POOL>
__global__ __launch_bounds__(256) void k_aggregate(const float* __restrict__ Y,
                                                   const float* __restrict__ dinv,
                                                   const float* __restrict__ bias,
                                                   const int* __restrict__ offsets,
                                                   const int* __restrict__ csr_src,
                                                   const float* __restrict__ Wf,
                                                   float* __restrict__ Yout,
                                                   float* __restrict__ pbuf, int n) {
    __shared__ float Wfs[64 * 64];   // used when FUSE (POOL variant: dead, still fits)
    __shared__ float4 sm4[4][16];
    int t = threadIdx.x, w = t >> 6, l = t & 63;
    int q = l >> 4, c = l & 15;
    if (FUSE) {
        const float4* W4 = (const float4*)Wf;
        float4* Ws4 = (float4*)Wfs;
#pragma unroll
        for (int j = 0; j < 4; j++) Ws4[t + 256 * j] = W4[t + 256 * j];
        __syncthreads();
    }
    const float4* Y4 = (const float4*)Y;
    int node = blockIdx.x * 4 + w;
    bool valid = node < n;
    float4 hval = make_float4(0.f, 0.f, 0.f, 0.f);
    float dv = 0.f;
    if (valid) {
        int beg = offsets[node], end = offsets[node + 1];
        int deg = end - beg;
        int sidx = (l < deg) ? csr_src[beg + l] : 0;  // one coalesced 256B load
        float4 acc = (q == 0) ? Y4[(size_t)node * 16 + c]
                              : make_float4(0.f, 0.f, 0.f, 0.f);  // self-loop
        for (int e0 = 0; e0 < deg; e0 += 16) {
#pragma unroll
            for (int u = 0; u < 4; u++) {
                int e = e0 + u * 4 + q;
                int s_sh = __shfl(sidx, e & 63);   // full-wave, uncond
                bool ok = e < deg;
                int s = (e < 64) ? s_sh : (ok ? csr_src[beg + e] : 0);
                float4 v = make_float4(0.f, 0.f, 0.f, 0.f);
                if (ok) v = Y4[(size_t)s * 16 + c];  // 16 lanes x 16B = row
                acc.x += v.x; acc.y += v.y; acc.z += v.z; acc.w += v.w;
            }
        }
        // reduce across the 4 edge slots (lane bits 4,5) -> all lanes hold sum
#pragma unroll
        for (int m = 16; m <= 32; m <<= 1) {
            acc.x += __shfl_xor(acc.x, m);
            acc.y += __shfl_xor(acc.y, m);
            acc.z += __shfl_xor(acc.z, m);
            acc.w += __shfl_xor(acc.w, m);
        }
        dv = dinv[node];
        float4 b4 = ((const float4*)bias)[c];
        hval.x = fmaxf(dv * acc.x + b4.x, 0.f);
        hval.y = fmaxf(dv * acc.y + b4.y, 0.f);
        hval.z = fmaxf(dv * acc.z + b4.z, 0.f);
        hval.w = fmaxf(dv * acc.w + b4.w, 0.f);
    }
    if (FUSE) {
        // all lanes hold h[4c..4c+3]; lane m (m<16) sources rows 4m..4m+3.
        // y2[node][l] = dv * sum_k h[k]*Wf[k][l]
        if (valid) {
            float acc2 = 0.f;
#pragma unroll
            for (int m = 0; m < 16; m++) {
                float rx = __shfl(hval.x, m);
                float ry = __shfl(hval.y, m);
                float rz = __shfl(hval.z, m);
                float rw = __shfl(hval.w, m);
                acc2 += rx * Wfs[(4 * m + 0) * 64 + l] + ry * Wfs[(4 * m + 1) * 64 + l]
                      + rz * Wfs[(4 * m + 2) * 64 + l] + rw * Wfs[(4 * m + 3) * 64 + l];
            }
            Yout[(size_t)node * 64 + l] = dv * acc2;
        }
    } else if (!POOL) {
        if (valid && q == 0) ((float4*)Yout)[(size_t)node * 16 + c] = hval;
    }
    if (POOL) {
        if (q == 0) sm4[w][c] = valid ? hval : make_float4(0.f, 0.f, 0.f, 0.f);
        __syncthreads();
        if (t < 16) {
            float4 a = sm4[0][t], b = sm4[1][t], d = sm4[2][t], e = sm4[3][t];
            float4 s;
            s.x = (a.x + b.x) + (d.x + e.x);
            s.y = (a.y + b.y) + (d.y + e.y);
            s.z = (a.z + b.z) + (d.z + e.z);
            s.w = (a.w + b.w) + (d.w + e.w);
            ((float4*)pbuf)[(size_t)blockIdx.x * 16 + t] = s;
        }
    }
}

__global__ void k_mean_final(const float* __restrict__ pbuf, float* __restrict__ g,
                             int nrows) {
    __shared__ float part[256];
    int t = threadIdx.x, w = t >> 6, f = t & 63;
    float local = 0.f;
    for (int r = blockIdx.x * 4 + w; r < nrows; r += gridDim.x * 4)
        local += pbuf[(size_t)r * 64 + f];
    part[t] = local;
    __syncthreads();
    if (w == 0) {
        float tot = part[f] + part[64 + f] + part[128 + f] + part[192 + f];
        atomicAdd(&g[f], tot);
    }
}

__global__ void k_readout(const float* __restrict__ g, const float* __restrict__ Wr,
                          const float* __restrict__ br, float* __restrict__ out,
                          float invn) {
    __shared__ float gl[64];
    int t = threadIdx.x;
    if (t < 64) gl[t] = g[t] * invn;
    __syncthreads();
    float acc = br[t];
#pragma unroll
    for (int k = 0; k < 64; k++) acc += gl[k] * Wr[k * 128 + t];
    out[t] = acc;
}

extern "C" void kernel_launch(void* const* d_in, const int* in_sizes, int n_in,
                              void* d_out, int out_size, void* d_ws, size_t ws_size,
                              hipStream_t stream) {
    const float* x  = (const float*)d_in[0];
    const int*   ei = (const int*)d_in[1];   // int32 on device (JAX x64 off)
    const float* W1 = (const float*)d_in[2];
    const float* b1 = (const float*)d_in[3];
    const float* W2 = (const float*)d_in[4];
    const float* b2 = (const float*)d_in[5];
    const float* Wr = (const float*)d_in[6];
    const float* br = (const float*)d_in[7];
    float* out = (float*)d_out;

    int n = in_sizes[0] / 64;   // 50000
    int E = in_sizes[1] / 2;    // 800000
    const int* src = ei;
    const int* dst = ei + E;

    int NB  = (n + 63) / 64;        // 782 buckets of 64 nodes
    int nch = (E + CH - 1) / CH;    // 196 chunks

    // workspace layout (~33 MB)
    char* p = (char*)d_ws;
    float* y1 = (float*)p;     p += (size_t)n * 64 * sizeof(float);
    float* y2 = (float*)p;     p += (size_t)n * 64 * sizeof(float);
    float* dinv = (float*)p;   p += (size_t)n * sizeof(float);
    float* g = (float*)p;      p += 64 * sizeof(float);
    int* staged = (int*)p;     p += (size_t)E * sizeof(int);
    int* csr_src = (int*)p;    p += (size_t)E * sizeof(int);
    int* offsets = (int*)p;    p += (size_t)(n + 1) * sizeof(int);
    int* histmat = (int*)p;    p += (size_t)nch * NB * sizeof(int);  // chunk-major
    int* tot = (int*)p;        p += (size_t)NB * sizeof(int);
    int* bstart = (int*)p;     p += (size_t)(NB + 1) * sizeof(int);

    int gb = (n + 3) / 4;  // 12500 aggregate blocks (one wave per node)

    hipMemsetAsync(g, 0, 64 * sizeof(float), stream);
    k_bucket_hist<<<nch, 256, 0, stream>>>(dst, histmat, E, NB);
    k_colscan<<<(NB + 255) / 256, 256, 0, stream>>>(histmat, tot, NB, nch);
    k_scanb<<<1, 256, 0, stream>>>(tot, bstart, offsets, NB, E, n);
    k_bucket_scatter<<<nch, 256, 0, stream>>>(src, dst, histmat, bstart, staged, E, NB);
    k_local_sort<<<NB, 256, 0, stream>>>(staged, bstart, csr_src, offsets, dinv, n);

    k_gemm_scale<<<(n + 15) / 16, 256, 0, stream>>>(x, W1, dinv, y1, n);
    // layer-1 aggregate fused with GEMM2: y2 = dinv * (relu(...) @ W2)
    k_aggregate<true, false><<<gb, 256, 0, stream>>>(y1, dinv, b1, offsets, csr_src,
                                                     W2, y2, nullptr, n);
    // layer-2 aggregate + pooled partial means (pbuf aliases dead y1)
    float* pbuf = y1;
    k_aggregate<false, true><<<gb, 256, 0, stream>>>(y2, dinv, b2, offsets, csr_src,
                                                     nullptr, nullptr, pbuf, n);

    k_mean_final<<<64, 256, 0, stream>>>(pbuf, g, gb);
    k_readout<<<1, 128, 0, stream>>>(g, Wr, br, out, 1.0f / (float)n);
}

// Round 8
// 233.651 us; speedup vs baseline: 1.0046x; 1.0046x over previous
//
#include <hip/hip_runtime.h>
#include <math.h>

// SimpleGCN: h1 = relu(GCN(x,W1,b1)); h2 = relu(GCN(h1,W2,b2));
// g = mean(h2, axis=0); out = (g@Wr + br) -> 128 fp32.
// GCN(x,W,b)[d] = dinv[d]*( sum_{s in N(d)} y[s] + y[d] ) + b,
//   y = dinv * (x@W), dinv[i] = (1+indeg[i])^-0.5.
//
// R7 post-mortem: shfl index-prefetch regressed (+20us/aggregate — bpermute
// in the gather chain + dual-path codegen); FUSE epilogue added 128 LDS
// ops/lane. Both reverted.
// R8 theory: aggregate is outstanding-miss bound at LLC latency (random
// 256B gathers over 12.8MB vs 4MB/XCD L2 -> FETCH pinned at ~81MB).
// Fix: FEATURE-QUARTER layout Y[4][n][16] (3.2MB/quarter fits L2), 4
// pass-major aggregate passes so gathers hit L2; csr indices as ushort.

#define CH 4096    // edges per chunk-block in hist/scatter
#define MAXNB 1024 // NB = ceil(n/64) <= 1024 (n <= 65536)

__global__ __launch_bounds__(256) void k_bucket_hist(const int* __restrict__ dst,
                                                     int* __restrict__ histmat,
                                                     int E, int NB) {
    __shared__ int ih[MAXNB];
    int t = threadIdx.x;
    for (int k = t; k < NB; k += 256) ih[k] = 0;
    __syncthreads();
    int base = blockIdx.x * CH;
    for (int i = 0; i < CH; i += 256) {
        int e = base + i + t;
        if (e < E) atomicAdd(&ih[dst[e] >> 6], 1);
    }
    __syncthreads();
    for (int k = t; k < NB; k += 256) histmat[(size_t)blockIdx.x * NB + k] = ih[k];
}

// thread per bucket: exclusive prefix over chunks in place + total.
__global__ __launch_bounds__(256) void k_colscan(int* __restrict__ histmat,
                                                 int* __restrict__ tot,
                                                 int NB, int nch) {
    int k = blockIdx.x * 256 + threadIdx.x;
    if (k >= NB) return;
    int run = 0;
    int b = 0;
    for (; b + 8 <= nch; b += 8) {
        int v[8];
#pragma unroll
        for (int u = 0; u < 8; u++) v[u] = histmat[(size_t)(b + u) * NB + k];
#pragma unroll
        for (int u = 0; u < 8; u++) {
            int x = v[u];
            histmat[(size_t)(b + u) * NB + k] = run;
            run += x;
        }
    }
    for (; b < nch; b++) {
        int x = histmat[(size_t)b * NB + k];
        histmat[(size_t)b * NB + k] = run;
        run += x;
    }
    tot[k] = run;
}

// single block: exclusive scan of NB (<=1024) totals -> bstart; tails.
__global__ __launch_bounds__(256) void k_scanb(const int* __restrict__ tot,
                                               int* __restrict__ bstart,
                                               int* __restrict__ offsets,
                                               int NB, int E, int n) {
    __shared__ int sc[256];
    __shared__ int carry;
    int t = threadIdx.x;
    if (t == 0) carry = 0;
    __syncthreads();
    int nchunk = (NB + 255) / 256;
    for (int c = 0; c < nchunk; c++) {
        int idx = c * 256 + t;
        int v = (idx < NB) ? tot[idx] : 0;
        sc[t] = v;
        __syncthreads();
        for (int off = 1; off < 256; off <<= 1) {
            int x = (t >= off) ? sc[t - off] : 0;
            __syncthreads();
            sc[t] += x;
            __syncthreads();
        }
        if (idx < NB) bstart[idx] = sc[t] - v + carry;
        __syncthreads();
        if (t == 0) carry += sc[255];
        __syncthreads();
    }
    if (t == 0) { bstart[NB] = E; offsets[n] = E; }
}

__global__ __launch_bounds__(256) void k_bucket_scatter(const int* __restrict__ src,
                                                        const int* __restrict__ dst,
                                                        const int* __restrict__ histmat,
                                                        const int* __restrict__ bstart,
                                                        int* __restrict__ staged,
                                                        int E, int NB) {
    __shared__ int cur[MAXNB];
    int t = threadIdx.x;
    for (int k = t; k < NB; k += 256)
        cur[k] = bstart[k] + histmat[(size_t)blockIdx.x * NB + k];
    __syncthreads();
    int base = blockIdx.x * CH;
    for (int i = 0; i < CH; i += 256) {
        int e = base + i + t;
        if (e < E) {
            int d = dst[e];
            int pos = atomicAdd(&cur[d >> 6], 1);
            staged[pos] = (src[e] << 6) | (d & 63);  // n<=65536 -> fits
        }
    }
}

// one block per bucket: counting-sort staged run into node-granular CSR
// (ushort indices, n<=65536); emit per-node offsets + dinv.
__global__ __launch_bounds__(256) void k_local_sort(const int* __restrict__ staged,
                                                    const int* __restrict__ bstart,
                                                    unsigned short* __restrict__ csr,
                                                    int* __restrict__ offsets,
                                                    float* __restrict__ dinv, int n) {
    __shared__ int cnt[64];
    __shared__ int pos[64];
    __shared__ int cur[64];
    int t = threadIdx.x;
    if (t < 64) cnt[t] = 0;
    __syncthreads();
    int k = blockIdx.x;
    int beg = bstart[k], end = bstart[k + 1];
    for (int e = beg + t; e < end; e += 256) atomicAdd(&cnt[staged[e] & 63], 1);
    __syncthreads();
    if (t == 0) {
        int run = 0;
        for (int i = 0; i < 64; i++) { pos[i] = run; run += cnt[i]; }
    }
    __syncthreads();
    if (t < 64) {
        cur[t] = pos[t];
        int node = k * 64 + t;
        if (node < n) {
            offsets[node] = beg + pos[t];
            dinv[node] = 1.0f / sqrtf((float)(cnt[t] + 1));  // + self-loop
        }
    }
    __syncthreads();
    for (int e = beg + t; e < end; e += 256) {
        int pk = staged[e];
        int p = atomicAdd(&cur[pk & 63], 1);
        csr[beg + p] = (unsigned short)(pk >> 6);
    }
}

// Y[i,:] = dinv[i]*(X[i,:] @ W), OUTPUT in quarter-major Yq[f>>4][i][f&15].
// QIN: input also quarter-major. 16 rows/block, 4 rows/wave.
template <bool QIN>
__global__ __launch_bounds__(256) void k_gemm_scale(const float* __restrict__ X,
                                                    const float* __restrict__ W,
                                                    const float* __restrict__ dinv,
                                                    float* __restrict__ Y, int n) {
    __shared__ float Ws[64 * 64];
    __shared__ float xs[16][64];
    int t = threadIdx.x, w = t >> 6, f = t & 63;
    const float4* W4 = (const float4*)W;
    float4* Ws4 = (float4*)Ws;
#pragma unroll
    for (int j = 0; j < 4; j++) Ws4[t + 256 * j] = W4[t + 256 * j];
    int r0 = blockIdx.x * 16;
#pragma unroll
    for (int i = 0; i < 4; i++) {
        int r = r0 + w * 4 + i;
        float v = 0.f;
        if (r < n)
            v = QIN ? X[((size_t)(f >> 4) * n + r) * 16 + (f & 15)]
                    : X[(size_t)r * 64 + f];
        xs[w * 4 + i][f] = v;
    }
    __syncthreads();
    float acc[4] = {0.f, 0.f, 0.f, 0.f};
#pragma unroll 8
    for (int k = 0; k < 64; k++) {
        float wv = Ws[k * 64 + f];
#pragma unroll
        for (int i = 0; i < 4; i++) acc[i] += xs[w * 4 + i][k] * wv;
    }
#pragma unroll
    for (int i = 0; i < 4; i++) {
        int r = r0 + w * 4 + i;
        if (r < n) Y[((size_t)(f >> 4) * n + r) * 16 + (f & 15)] = dinv[r] * acc[i];
    }
}

__device__ __forceinline__ float4 xor4(float4 a, int m) {
    a.x += __shfl_xor(a.x, m);
    a.y += __shfl_xor(a.y, m);
    a.z += __shfl_xor(a.z, m);
    a.w += __shfl_xor(a.w, m);
    return a;
}

// Quarter-pass aggregate. Grid = 4*nblk, pass-major (pass = blockIdx/nblk)
// so co-resident blocks share one 3.2MB L2-resident Y quarter.
// Wave handles 4 nodes; lane l = i*16 + j*4 + c (i=node, j=edge slot,
// c=float4 col of the 16-float quarter row). Gather: one dwordx4 instr
// covers 16 edges (4 per node). Reduce over j: xor4(4),xor4(8).
// POOL: also reduce over i + cross-wave LDS -> per-block partial rows
// pbuf[blk][pass*16..] (flat 64-wide rows, feature f = pass*16+cc).
template <bool POOL>
__global__ __launch_bounds__(256) void k_aggregate_q(const float* __restrict__ Y,
                                                     const float* __restrict__ dinv,
                                                     const float* __restrict__ bias,
                                                     const int* __restrict__ offsets,
                                                     const unsigned short* __restrict__ csr,
                                                     float* __restrict__ Yout,
                                                     float* __restrict__ pbuf,
                                                     int n, int nblk) {
    __shared__ float4 sm4[4][4];
    int t = threadIdx.x, w = t >> 6, l = t & 63;
    int i = l >> 4, j = (l >> 2) & 3, c = l & 3;
    int pass = blockIdx.x / nblk, blk = blockIdx.x - pass * nblk;
    int node = blk * 16 + w * 4 + i;
    const float4* Y4 = (const float4*)Y + (size_t)pass * n * 4;
    bool valid = node < n;
    float4 acc = make_float4(0.f, 0.f, 0.f, 0.f);
    float dv = 0.f;
    if (valid) {
        int beg = offsets[node];
        int deg = offsets[node + 1] - beg;
        dv = dinv[node];
        if (j == 0) acc = Y4[(size_t)node * 4 + c];  // self-loop quarter
        for (int e0 = 0; e0 < deg; e0 += 16) {
#pragma unroll
            for (int u = 0; u < 4; u++) {
                int e = e0 + u * 4 + j;
                if (e < deg) {
                    int s = csr[beg + e];
                    float4 v = Y4[(size_t)s * 4 + c];
                    acc.x += v.x; acc.y += v.y; acc.z += v.z; acc.w += v.w;
                }
            }
        }
    }
    acc = xor4(acc, 4);   // reduce over edge slots j
    acc = xor4(acc, 8);
    float4 b4 = ((const float4*)bias)[pass * 4 + c];
    float4 h = make_float4(0.f, 0.f, 0.f, 0.f);
    if (valid) {
        h.x = fmaxf(dv * acc.x + b4.x, 0.f);
        h.y = fmaxf(dv * acc.y + b4.y, 0.f);
        h.z = fmaxf(dv * acc.z + b4.z, 0.f);
        h.w = fmaxf(dv * acc.w + b4.w, 0.f);
    }
    if (!POOL) {
        if (valid && j == 0)
            ((float4*)Yout + (size_t)pass * n * 4)[(size_t)node * 4 + c] = h;
    } else {
        h = xor4(h, 16);  // reduce over nodes i
        h = xor4(h, 32);
        if (l < 4) sm4[w][c] = h;
        __syncthreads();
        if (t < 4) {
            float4 a = sm4[0][t], b = sm4[1][t], d = sm4[2][t], e = sm4[3][t];
            float4 s;
            s.x = (a.x + b.x) + (d.x + e.x);
            s.y = (a.y + b.y) + (d.y + e.y);
            s.z = (a.z + b.z) + (d.z + e.z);
            s.w = (a.w + b.w) + (d.w + e.w);
            ((float4*)pbuf)[((size_t)blk * 4 + pass) * 4 + t] = s;
        }
    }
}

__global__ void k_mean_final(const float* __restrict__ pbuf, float* __restrict__ g,
                             int nrows) {
    __shared__ float part[256];
    int t = threadIdx.x, w = t >> 6, f = t & 63;
    float local = 0.f;
    for (int r = blockIdx.x * 4 + w; r < nrows; r += gridDim.x * 4)
        local += pbuf[(size_t)r * 64 + f];
    part[t] = local;
    __syncthreads();
    if (w == 0) {
        float tot = part[f] + part[64 + f] + part[128 + f] + part[192 + f];
        atomicAdd(&g[f], tot);
    }
}

__global__ void k_readout(const float* __restrict__ g, const float* __restrict__ Wr,
                          const float* __restrict__ br, float* __restrict__ out,
                          float invn) {
    __shared__ float gl[64];
    int t = threadIdx.x;
    if (t < 64) gl[t] = g[t] * invn;
    __syncthreads();
    float acc = br[t];
#pragma unroll
    for (int k = 0; k < 64; k++) acc += gl[k] * Wr[k * 128 + t];
    out[t] = acc;
}

extern "C" void kernel_launch(void* const* d_in, const int* in_sizes, int n_in,
                              void* d_out, int out_size, void* d_ws, size_t ws_size,
                              hipStream_t stream) {
    const float* x  = (const float*)d_in[0];
    const int*   ei = (const int*)d_in[1];   // int32 on device (JAX x64 off)
    const float* W1 = (const float*)d_in[2];
    const float* b1 = (const float*)d_in[3];
    const float* W2 = (const float*)d_in[4];
    const float* b2 = (const float*)d_in[5];
    const float* Wr = (const float*)d_in[6];
    const float* br = (const float*)d_in[7];
    float* out = (float*)d_out;

    int n = in_sizes[0] / 64;   // 50000
    int E = in_sizes[1] / 2;    // 800000
    const int* src = ei;
    const int* dst = ei + E;

    int NB   = (n + 63) / 64;      // 782 buckets of 64 nodes
    int nch  = (E + CH - 1) / CH;  // 196 chunks
    int nblk = (n + 15) / 16;      // 3125 aggregate blocks per pass

    // workspace layout (~32 MB)
    char* p = (char*)d_ws;
    float* y1 = (float*)p;     p += (size_t)n * 64 * sizeof(float);   // quarter-major
    float* y2 = (float*)p;     p += (size_t)n * 64 * sizeof(float);   // quarter-major
    float* dinv = (float*)p;   p += (size_t)n * sizeof(float);
    float* g = (float*)p;      p += 64 * sizeof(float);
    int* staged = (int*)p;     p += (size_t)E * sizeof(int);
    int* offsets = (int*)p;    p += (size_t)(n + 1) * sizeof(int);
    int* histmat = (int*)p;    p += (size_t)nch * NB * sizeof(int);   // chunk-major
    int* tot = (int*)p;        p += (size_t)NB * sizeof(int);
    int* bstart = (int*)p;     p += (size_t)(NB + 1) * sizeof(int);
    unsigned short* csr = (unsigned short*)p; p += (size_t)E * sizeof(unsigned short);

    hipMemsetAsync(g, 0, 64 * sizeof(float), stream);
    k_bucket_hist<<<nch, 256, 0, stream>>>(dst, histmat, E, NB);
    k_colscan<<<(NB + 255) / 256, 256, 0, stream>>>(histmat, tot, NB, nch);
    k_scanb<<<1, 256, 0, stream>>>(tot, bstart, offsets, NB, E, n);
    k_bucket_scatter<<<nch, 256, 0, stream>>>(src, dst, histmat, bstart, staged, E, NB);
    k_local_sort<<<NB, 256, 0, stream>>>(staged, bstart, csr, offsets, dinv, n);

    k_gemm_scale<false><<<(n + 15) / 16, 256, 0, stream>>>(x, W1, dinv, y1, n);
    k_aggregate_q<false><<<4 * nblk, 256, 0, stream>>>(y1, dinv, b1, offsets, csr,
                                                       y2, nullptr, n, nblk);
    // y2 now holds h1 (quarter-major); reuse y1 for layer-2 linear output
    k_gemm_scale<true><<<(n + 15) / 16, 256, 0, stream>>>(y2, W2, dinv, y1, n);
    float* pbuf = y2;  // dead after gemm2 -> per-block partial rows
    k_aggregate_q<true><<<4 * nblk, 256, 0, stream>>>(y1, dinv, b2, offsets, csr,
                                                      nullptr, pbuf, n, nblk);

    k_mean_final<<<64, 256, 0, stream>>>(pbuf, g, nblk);
    k_readout<<<1, 128, 0, stream>>>(g, Wr, br, out, 1.0f / (float)n);
}